// Round 1
// baseline (675.296 us; speedup 1.0000x reference)
//
#include <hip/hip_runtime.h>

#define EPS 1e-8f

// One row of D=128 floats per 32-lane group; lane g owns columns [4g, 4g+4).
// Block = 256 threads => 8 rows per block-iteration. Grid-stride over rows.
__global__ __launch_bounds__(256) void pdf_normal_kernel(
    const float* __restrict__ x,
    const float* __restrict__ mean,
    const float* __restrict__ var,
    float* __restrict__ out,
    int N)
{
    const int t = threadIdx.x;
    const int g = t & 31;           // column-group lane within the 32-lane row team
    const int rowInBlock = t >> 5;  // 0..7

    // Per-thread column constants (read once; served from L1/L2 thereafter).
    const float4 m = reinterpret_cast<const float4*>(mean)[g];
    const float4 v = reinterpret_cast<const float4*>(var)[g];
    const float ve0 = v.x + EPS, ve1 = v.y + EPS, ve2 = v.z + EPS, ve3 = v.w + EPS;

    // exp(-0.5*d^2/ve) == exp2(d^2 * (-0.5/ln2)/ve)
    const float NHIL2 = -0.72134752044448170368f; // -0.5 / ln(2)
    const float c0 = NHIL2 / ve0;
    const float c1 = NHIL2 / ve1;
    const float c2 = NHIL2 / ve2;
    const float c3 = NHIL2 / ve3;

    // Denominator: sum of var_eps over all 128 columns (width-32 reduction).
    float vs = ve0 + ve1 + ve2 + ve3;
    #pragma unroll
    for (int off = 16; off; off >>= 1) vs += __shfl_xor(vs, off, 32);
    const float inv_den = 1.0f / vs;

    const long stride = (long)gridDim.x * 8;
    for (long row = (long)blockIdx.x * 8 + rowInBlock; row < N; row += stride) {
        const float4 xv = reinterpret_cast<const float4*>(x + row * 128)[g];
        const float d0 = xv.x - m.x;
        const float d1 = xv.y - m.y;
        const float d2 = xv.z - m.z;
        const float d3 = xv.w - m.w;
        float s = exp2f(d0 * d0 * c0) + exp2f(d1 * d1 * c1)
                + exp2f(d2 * d2 * c2) + exp2f(d3 * d3 * c3);
        #pragma unroll
        for (int off = 16; off; off >>= 1) s += __shfl_xor(s, off, 32);
        if (g == 0) out[row] = s * inv_den;
    }
}

extern "C" void kernel_launch(void* const* d_in, const int* in_sizes, int n_in,
                              void* d_out, int out_size, void* d_ws, size_t ws_size,
                              hipStream_t stream) {
    const float* x    = (const float*)d_in[0];
    const float* mean = (const float*)d_in[1];
    const float* var  = (const float*)d_in[2];
    float* out = (float*)d_out;
    const int N = out_size; // 1048576 rows

    // 8 rows per block per iteration; 8192 blocks => ~16 grid-stride iters,
    // plenty of waves to saturate HBM on 256 CUs.
    int rowsPerBlock = 8;
    int maxBlocks = 8192;
    int needed = (N + rowsPerBlock - 1) / rowsPerBlock;
    int grid = needed < maxBlocks ? needed : maxBlocks;

    pdf_normal_kernel<<<grid, 256, 0, stream>>>(x, mean, var, out, N);
}